// Round 1
// baseline (1087.151 us; speedup 1.0000x reference)
//
#include <hip/hip_runtime.h>
#include <hip/hip_bf16.h>
#include <cmath>
#include <cstddef>

// Problem constants: B=2, L=2048, H=16, HD=64, C=1024
// qkv GEMM: M=4096, K=1024, N=3072
// attention: 32 (b,h) pairs, L=2048, HD=64, non-causal full softmax
// out GEMM:  M=4096, K=1024, N=1024

// ---------------------------------------------------------------------------
// QKV projection: x[4096][1024] @ w_qkv[1024][3072] + b_qkv
// Epilogue scatters into q/k/v each [B,H,L,HD] = [2,16,2048,64].
// 64x64 tile, BK=16, 256 threads, 4x4 accum per thread.
// ---------------------------------------------------------------------------
__global__ __launch_bounds__(256) void ga_qkv_gemm(const float* __restrict__ X,
                                                   const float* __restrict__ W,
                                                   const float* __restrict__ bias,
                                                   float* __restrict__ q,
                                                   float* __restrict__ k,
                                                   float* __restrict__ v) {
  __shared__ float As[16][68];  // [kk][row] transposed
  __shared__ float Bs[16][68];  // [kk][col]
  const int m0 = blockIdx.y * 64;
  const int n0 = blockIdx.x * 64;
  const int t  = threadIdx.x;
  const int ty = t >> 4, tx = t & 15;
  const int ar = t >> 2, ac = (t & 3) * 4;   // A loader: row 0..63, col chunk
  const int br = t >> 4, bc = (t & 15) * 4;  // B loader: row 0..15, col chunk

  float acc[4][4] = {};
  for (int k0 = 0; k0 < 1024; k0 += 16) {
    float4 a4 = *reinterpret_cast<const float4*>(X + (size_t)(m0 + ar) * 1024 + k0 + ac);
    float4 b4 = *reinterpret_cast<const float4*>(W + (size_t)(k0 + br) * 3072 + n0 + bc);
    __syncthreads();
    As[ac + 0][ar] = a4.x;
    As[ac + 1][ar] = a4.y;
    As[ac + 2][ar] = a4.z;
    As[ac + 3][ar] = a4.w;
    *reinterpret_cast<float4*>(&Bs[br][bc]) = b4;
    __syncthreads();
#pragma unroll
    for (int kk = 0; kk < 16; ++kk) {
      float a[4], b[4];
#pragma unroll
      for (int i = 0; i < 4; ++i) a[i] = As[kk][ty * 4 + i];
#pragma unroll
      for (int j = 0; j < 4; ++j) b[j] = Bs[kk][tx * 4 + j];
#pragma unroll
      for (int i = 0; i < 4; ++i)
#pragma unroll
        for (int j = 0; j < 4; ++j) acc[i][j] += a[i] * b[j];
    }
  }
  // epilogue: col tile (64-aligned) lies entirely within one s (q/k/v) and one head
  const int s = n0 >> 10;
  const int h = (n0 >> 6) & 15;
  float* dst = (s == 0) ? q : (s == 1) ? k : v;
  const float4 bias4 = *reinterpret_cast<const float4*>(bias + n0 + tx * 4);
#pragma unroll
  for (int i = 0; i < 4; ++i) {
    int m = m0 + ty * 4 + i;
    int bb = m >> 11, l = m & 2047;
    float4 o;
    o.x = acc[i][0] + bias4.x;
    o.y = acc[i][1] + bias4.y;
    o.z = acc[i][2] + bias4.z;
    o.w = acc[i][3] + bias4.w;
    *reinterpret_cast<float4*>(dst + ((size_t)((bb * 16 + h) * 2048 + l)) * 64 + tx * 4) = o;
  }
}

// ---------------------------------------------------------------------------
// RoPE in-place on q and k ([B,H,L,HD]).  theta = l * freqs[h][f], f = 0..31,
// pair (f, f+32).  f32 theta + accurate sincosf (matches the f32 reference
// pipeline; sincosf does proper range reduction for large theta).
// ---------------------------------------------------------------------------
__global__ __launch_bounds__(256) void ga_rope(float* __restrict__ q,
                                               float* __restrict__ k,
                                               const float* __restrict__ freqs) {
  int tid = blockIdx.x * 256 + threadIdx.x;
  int f   = tid & 31;
  int row = tid >> 5;  // 0 .. B*H*L-1 = 65535
  int l = row & 2047;
  int h = (row >> 11) & 15;
  float theta = (float)l * freqs[h * 32 + f];
  float s, c;
  sincosf(theta, &s, &c);
  float* qp = q + (size_t)row * 64;
  float q1 = qp[f], q2 = qp[f + 32];
  qp[f]      = q1 * c - q2 * s;
  qp[f + 32] = q1 * s + q2 * c;
  float* kp = k + (size_t)row * 64;
  float k1 = kp[f], k2 = kp[f + 32];
  kp[f]      = k1 * c - k2 * s;
  kp[f + 32] = k1 * s + k2 * c;
}

// ---------------------------------------------------------------------------
// Flash attention (non-causal): per block one (b,h) and a 64-row Q tile;
// iterate over 32 K/V tiles of 64 keys.  Online softmax.  f32 outer-product
// compute, 4x4 per thread.  Output written as [B,L,C] for the out-proj GEMM.
// ---------------------------------------------------------------------------
__global__ __launch_bounds__(256) void ga_attn(const float* __restrict__ q,
                                               const float* __restrict__ k,
                                               const float* __restrict__ v,
                                               float* __restrict__ out) {
  __shared__ float Qs[64][68];  // [d][qrow]
  __shared__ float Ks[64][68];  // [d][kcol]
  __shared__ float Vs[64][68];  // [key][d]
  __shared__ float Ss[64][68];  // [qrow][key]
  __shared__ float red_m[64], red_l[64], red_alpha[64];

  const int bh = blockIdx.y;       // b*16 + h
  const int q0 = blockIdx.x * 64;  // q row tile base
  const float* qbase = q + (size_t)bh * 2048 * 64;
  const float* kbase = k + (size_t)bh * 2048 * 64;
  const float* vbase = v + (size_t)bh * 2048 * 64;

  const int t  = threadIdx.x;
  const int ty = t >> 4, tx = t & 15;
  const int lr  = t >> 2;         // loader row 0..63
  const int lc0 = (t & 3) * 16;   // loader col chunk base

  // load Q tile transposed into Qs[d][row]
#pragma unroll
  for (int u = 0; u < 4; ++u) {
    int col = lc0 + u * 4;
    float4 a4 = *reinterpret_cast<const float4*>(qbase + (size_t)(q0 + lr) * 64 + col);
    Qs[col + 0][lr] = a4.x;
    Qs[col + 1][lr] = a4.y;
    Qs[col + 2][lr] = a4.z;
    Qs[col + 3][lr] = a4.w;
  }
  if (t < 64) {
    red_m[t] = -3.0e38f;
    red_l[t] = 0.0f;
  }

  float acc[4][4] = {};

  for (int k0 = 0; k0 < 2048; k0 += 64) {
    // stage K (transposed) and V (natural) through registers
    float4 kreg[4], vreg[4];
#pragma unroll
    for (int u = 0; u < 4; ++u) {
      int col = lc0 + u * 4;
      kreg[u] = *reinterpret_cast<const float4*>(kbase + (size_t)(k0 + lr) * 64 + col);
      vreg[u] = *reinterpret_cast<const float4*>(vbase + (size_t)(k0 + lr) * 64 + col);
    }
    __syncthreads();  // previous iteration done reading Ks/Vs/Ss
#pragma unroll
    for (int u = 0; u < 4; ++u) {
      int col = lc0 + u * 4;
      Ks[col + 0][lr] = kreg[u].x;
      Ks[col + 1][lr] = kreg[u].y;
      Ks[col + 2][lr] = kreg[u].z;
      Ks[col + 3][lr] = kreg[u].w;
      *reinterpret_cast<float4*>(&Vs[lr][col]) = vreg[u];
    }
    __syncthreads();

    // S = (Q K^T) * 0.125
    float sacc[4][4] = {};
#pragma unroll 16
    for (int kk = 0; kk < 64; ++kk) {
      float a[4], b[4];
#pragma unroll
      for (int i = 0; i < 4; ++i) a[i] = Qs[kk][ty * 4 + i];
#pragma unroll
      for (int j = 0; j < 4; ++j) b[j] = Ks[kk][tx * 4 + j];
#pragma unroll
      for (int i = 0; i < 4; ++i)
#pragma unroll
        for (int j = 0; j < 4; ++j) sacc[i][j] += a[i] * b[j];
    }
#pragma unroll
    for (int i = 0; i < 4; ++i) {
      float4 o;
      o.x = sacc[i][0] * 0.125f;
      o.y = sacc[i][1] * 0.125f;
      o.z = sacc[i][2] * 0.125f;
      o.w = sacc[i][3] * 0.125f;
      *reinterpret_cast<float4*>(&Ss[ty * 4 + i][tx * 4]) = o;
    }
    __syncthreads();

    // online softmax: 4 threads per row
    {
      int sr = t >> 2;
      int c0 = (t & 3) * 16;
      float mx = -3.0e38f;
#pragma unroll
      for (int c = 0; c < 16; ++c) mx = fmaxf(mx, Ss[sr][c0 + c]);
      mx = fmaxf(mx, __shfl_xor(mx, 1));
      mx = fmaxf(mx, __shfl_xor(mx, 2));
      float m_old = red_m[sr];
      float m_new = fmaxf(m_old, mx);
      float sum = 0.0f;
#pragma unroll
      for (int c = 0; c < 16; ++c) {
        float p = __expf(Ss[sr][c0 + c] - m_new);
        Ss[sr][c0 + c] = p;
        sum += p;
      }
      sum += __shfl_xor(sum, 1);
      sum += __shfl_xor(sum, 2);
      if ((t & 3) == 0) {
        float alpha    = __expf(m_old - m_new);
        red_alpha[sr]  = alpha;
        red_m[sr]      = m_new;
        red_l[sr]      = red_l[sr] * alpha + sum;
      }
    }
    __syncthreads();

    // rescale accumulators, then O += P @ V
    float al[4];
#pragma unroll
    for (int i = 0; i < 4; ++i) al[i] = red_alpha[ty * 4 + i];
#pragma unroll
    for (int i = 0; i < 4; ++i)
#pragma unroll
      for (int j = 0; j < 4; ++j) acc[i][j] *= al[i];

#pragma unroll 16
    for (int kk = 0; kk < 64; ++kk) {
      float a[4], b[4];
#pragma unroll
      for (int i = 0; i < 4; ++i) a[i] = Ss[ty * 4 + i][kk];
#pragma unroll
      for (int j = 0; j < 4; ++j) b[j] = Vs[kk][tx * 4 + j];
#pragma unroll
      for (int i = 0; i < 4; ++i)
#pragma unroll
        for (int j = 0; j < 4; ++j) acc[i][j] += a[i] * b[j];
    }
  }

  // normalize and write out as [B, L, C]  (C index = h*64 + d)
  const int bb = bh >> 4, h = bh & 15;
  float* obase = out + ((size_t)(bb * 2048 + q0)) * 1024 + h * 64;
  float inv_l[4];
#pragma unroll
  for (int i = 0; i < 4; ++i) inv_l[i] = 1.0f / red_l[ty * 4 + i];
#pragma unroll
  for (int i = 0; i < 4; ++i) {
    float4 o;
    o.x = acc[i][0] * inv_l[i];
    o.y = acc[i][1] * inv_l[i];
    o.z = acc[i][2] * inv_l[i];
    o.w = acc[i][3] * inv_l[i];
    *reinterpret_cast<float4*>(obase + (size_t)(ty * 4 + i) * 1024 + tx * 4) = o;
  }
}

// ---------------------------------------------------------------------------
// Output projection: attn_out[4096][1024] @ w_out[1024][1024] + b_out -> d_out
// ---------------------------------------------------------------------------
__global__ __launch_bounds__(256) void ga_out_gemm(const float* __restrict__ A,
                                                   const float* __restrict__ W,
                                                   const float* __restrict__ bias,
                                                   float* __restrict__ out) {
  __shared__ float As[16][68];
  __shared__ float Bs[16][68];
  const int m0 = blockIdx.y * 64;
  const int n0 = blockIdx.x * 64;
  const int t  = threadIdx.x;
  const int ty = t >> 4, tx = t & 15;
  const int ar = t >> 2, ac = (t & 3) * 4;
  const int br = t >> 4, bc = (t & 15) * 4;

  float acc[4][4] = {};
  for (int k0 = 0; k0 < 1024; k0 += 16) {
    float4 a4 = *reinterpret_cast<const float4*>(A + (size_t)(m0 + ar) * 1024 + k0 + ac);
    float4 b4 = *reinterpret_cast<const float4*>(W + (size_t)(k0 + br) * 1024 + n0 + bc);
    __syncthreads();
    As[ac + 0][ar] = a4.x;
    As[ac + 1][ar] = a4.y;
    As[ac + 2][ar] = a4.z;
    As[ac + 3][ar] = a4.w;
    *reinterpret_cast<float4*>(&Bs[br][bc]) = b4;
    __syncthreads();
#pragma unroll
    for (int kk = 0; kk < 16; ++kk) {
      float a[4], b[4];
#pragma unroll
      for (int i = 0; i < 4; ++i) a[i] = As[kk][ty * 4 + i];
#pragma unroll
      for (int j = 0; j < 4; ++j) b[j] = Bs[kk][tx * 4 + j];
#pragma unroll
      for (int i = 0; i < 4; ++i)
#pragma unroll
        for (int j = 0; j < 4; ++j) acc[i][j] += a[i] * b[j];
    }
  }
  const float4 bias4 = *reinterpret_cast<const float4*>(bias + n0 + tx * 4);
#pragma unroll
  for (int i = 0; i < 4; ++i) {
    int m = m0 + ty * 4 + i;
    float4 o;
    o.x = acc[i][0] + bias4.x;
    o.y = acc[i][1] + bias4.y;
    o.z = acc[i][2] + bias4.z;
    o.w = acc[i][3] + bias4.w;
    *reinterpret_cast<float4*>(out + (size_t)m * 1024 + n0 + tx * 4) = o;
  }
}

// ---------------------------------------------------------------------------
extern "C" void kernel_launch(void* const* d_in, const int* in_sizes, int n_in,
                              void* d_out, int out_size, void* d_ws, size_t ws_size,
                              hipStream_t stream) {
  const float* x          = (const float*)d_in[0];
  const float* w_qkv      = (const float*)d_in[1];
  const float* b_qkv      = (const float*)d_in[2];
  const float* w_out      = (const float*)d_in[3];
  const float* b_out      = (const float*)d_in[4];
  const float* rope_freqs = (const float*)d_in[5];
  float* out = (float*)d_out;

  const size_t TSZ = (size_t)2 * 16 * 2048 * 64;  // 4,194,304 floats per tensor
  float* q        = (float*)d_ws;
  float* k        = q + TSZ;
  float* v        = k + TSZ;
  float* attn_out = v + TSZ;

  // 1) QKV projection, scattered into [B,H,L,HD] q/k/v
  hipLaunchKernelGGL(ga_qkv_gemm, dim3(48, 64), dim3(256), 0, stream,
                     x, w_qkv, b_qkv, q, k, v);
  // 2) RoPE in-place on q, k
  hipLaunchKernelGGL(ga_rope, dim3(8192), dim3(256), 0, stream, q, k, rope_freqs);
  // 3) flash attention -> attn_out [B,L,C]
  hipLaunchKernelGGL(ga_attn, dim3(32, 32), dim3(256), 0, stream, q, k, v, attn_out);
  // 4) output projection -> d_out
  hipLaunchKernelGGL(ga_out_gemm, dim3(16, 64), dim3(256), 0, stream,
                     attn_out, w_out, b_out, out);
}

// Round 2
// 416.733 us; speedup vs baseline: 2.6087x; 2.6087x over previous
//
#include <hip/hip_runtime.h>
#include <cstddef>
#include <cstdint>

// B=2, L=2048, H=16, HD=64, C=1024. All matmuls on bf16 MFMA, f32 accum.

typedef __attribute__((ext_vector_type(8))) short short8;
typedef __attribute__((ext_vector_type(4))) float f32x4;
typedef __attribute__((ext_vector_type(4))) unsigned short ushort4_t;

__device__ __forceinline__ unsigned short f2bf(float f) {
  union { float f; unsigned int u; } c{f};
  unsigned int u = c.u;
  u += 0x7fff + ((u >> 16) & 1);   // round-to-nearest-even
  return (unsigned short)(u >> 16);
}
__device__ __forceinline__ float bf2f(unsigned short h) {
  union { unsigned int u; float f; } c{((unsigned int)h) << 16};
  return c.f;
}

// ---------------------------------------------------------------------------
// f32 -> bf16 elementwise convert (vectorized)
// ---------------------------------------------------------------------------
__global__ __launch_bounds__(256) void cvt_f32_bf16(const float* __restrict__ src,
                                                    unsigned short* __restrict__ dst,
                                                    int n4) {
  int i = blockIdx.x * 256 + threadIdx.x;
  int stride = gridDim.x * 256;
  for (; i < n4; i += stride) {
    float4 v = reinterpret_cast<const float4*>(src)[i];
    ushort4_t o;
    o.x = f2bf(v.x); o.y = f2bf(v.y); o.z = f2bf(v.z); o.w = f2bf(v.w);
    reinterpret_cast<ushort4_t*>(dst)[i] = o;
  }
}

// ---------------------------------------------------------------------------
// W[K][N] f32  ->  WT[N][K] bf16   (64x64 tiles via LDS)
// ---------------------------------------------------------------------------
__global__ __launch_bounds__(256) void transpose_cvt(const float* __restrict__ W,
                                                     unsigned short* __restrict__ WT,
                                                     int K, int N) {
  __shared__ float T[64][65];
  const int n0 = blockIdx.x * 64, k0 = blockIdx.y * 64;
  const int t = threadIdx.x;
  const int r = t >> 4, c4 = (t & 15) * 4;
#pragma unroll
  for (int rr = 0; rr < 4; ++rr) {
    int kk = rr * 16 + r;
    float4 v = *reinterpret_cast<const float4*>(W + (size_t)(k0 + kk) * N + n0 + c4);
    T[kk][c4 + 0] = v.x; T[kk][c4 + 1] = v.y; T[kk][c4 + 2] = v.z; T[kk][c4 + 3] = v.w;
  }
  __syncthreads();
#pragma unroll
  for (int rr = 0; rr < 4; ++rr) {
    int nn = rr * 16 + r;
    ushort4_t o;
    o.x = f2bf(T[c4 + 0][nn]); o.y = f2bf(T[c4 + 1][nn]);
    o.z = f2bf(T[c4 + 2][nn]); o.w = f2bf(T[c4 + 3][nn]);
    *reinterpret_cast<ushort4_t*>(WT + (size_t)(n0 + nn) * K + k0 + c4) = o;
  }
}

// ---------------------------------------------------------------------------
// 128x128x(BK=32) bf16 MFMA GEMM, K=1024 fixed.  A[M][1024] bf16,
// Bt[N][1024] bf16 (pre-transposed).  EPI 0: qkv scatter epilogue (bf16
// q/k/v in [B,H,L,HD]);  EPI 1: f32 out + bias.
// ---------------------------------------------------------------------------
template <int EPI>
__global__ __launch_bounds__(256) void mm128(const unsigned short* __restrict__ A,
                                             const unsigned short* __restrict__ Bt,
                                             const float* __restrict__ bias,
                                             unsigned short* __restrict__ q,
                                             unsigned short* __restrict__ k,
                                             unsigned short* __restrict__ v,
                                             float* __restrict__ outf) {
  __shared__ unsigned short As[128][40];  // stride 80B: 16B-aligned rows, 2-way-free banks
  __shared__ unsigned short Bs[128][40];
  const int m0 = blockIdx.y * 128, n0 = blockIdx.x * 128;
  const int t = threadIdx.x, l = t & 63, w = t >> 6;
  const int wm = w >> 1, wn = w & 1;
  const int lr = l & 15, lg = l >> 4;
  const int lrow = t >> 1, lk = (t & 1) * 16;

  f32x4 acc[4][4] = {};
  for (int k0 = 0; k0 < 1024; k0 += 32) {
    const unsigned short* ap = A + (size_t)(m0 + lrow) * 1024 + k0 + lk;
    const unsigned short* bp = Bt + (size_t)(n0 + lrow) * 1024 + k0 + lk;
    short8 av0 = *reinterpret_cast<const short8*>(ap);
    short8 av1 = *reinterpret_cast<const short8*>(ap + 8);
    short8 bv0 = *reinterpret_cast<const short8*>(bp);
    short8 bv1 = *reinterpret_cast<const short8*>(bp + 8);
    __syncthreads();
    *reinterpret_cast<short8*>(&As[lrow][lk]) = av0;
    *reinterpret_cast<short8*>(&As[lrow][lk + 8]) = av1;
    *reinterpret_cast<short8*>(&Bs[lrow][lk]) = bv0;
    *reinterpret_cast<short8*>(&Bs[lrow][lk + 8]) = bv1;
    __syncthreads();
    short8 af[4], bf[4];
#pragma unroll
    for (int i = 0; i < 4; ++i)
      af[i] = *reinterpret_cast<const short8*>(&As[wm * 64 + i * 16 + lr][lg * 8]);
#pragma unroll
    for (int j = 0; j < 4; ++j)
      bf[j] = *reinterpret_cast<const short8*>(&Bs[wn * 64 + j * 16 + lr][lg * 8]);
#pragma unroll
    for (int i = 0; i < 4; ++i)
#pragma unroll
      for (int j = 0; j < 4; ++j)
        acc[i][j] = __builtin_amdgcn_mfma_f32_16x16x32_bf16(af[i], bf[j], acc[i][j], 0, 0, 0);
  }

  if constexpr (EPI == 0) {
#pragma unroll
    for (int j = 0; j < 4; ++j) {
      const int n = n0 + wn * 64 + j * 16 + lr;
      const float bb = bias[n];
      const int s = n >> 10, cc = n & 1023, h = cc >> 6, d = cc & 63;
      unsigned short* dst = (s == 0) ? q : (s == 1) ? k : v;
#pragma unroll
      for (int i = 0; i < 4; ++i)
#pragma unroll
        for (int r = 0; r < 4; ++r) {
          const int m = m0 + wm * 64 + i * 16 + lg * 4 + r;
          const int b = m >> 11, lseq = m & 2047;
          dst[(size_t)(((b << 4) + h) * 2048 + lseq) * 64 + d] = f2bf(acc[i][j][r] + bb);
        }
    }
  } else {
#pragma unroll
    for (int j = 0; j < 4; ++j) {
      const int n = n0 + wn * 64 + j * 16 + lr;
      const float bb = bias[n];
#pragma unroll
      for (int i = 0; i < 4; ++i)
#pragma unroll
        for (int r = 0; r < 4; ++r) {
          const int m = m0 + wm * 64 + i * 16 + lg * 4 + r;
          outf[(size_t)m * 1024 + n] = acc[i][j][r] + bb;
        }
    }
  }
}

// ---------------------------------------------------------------------------
// RoPE in-place on bf16 q,k ([bh][l][64]); folds 0.125 scale into q.
// ---------------------------------------------------------------------------
__global__ __launch_bounds__(256) void rope_bf(unsigned short* __restrict__ q,
                                               unsigned short* __restrict__ k,
                                               const float* __restrict__ freqs) {
  const int tid = blockIdx.x * 256 + threadIdx.x;
  const int f = tid & 31, row = tid >> 5;
  const int lseq = row & 2047, h = (row >> 11) & 15;
  const float th = (float)lseq * freqs[h * 32 + f];
  float s, c;
  sincosf(th, &s, &c);
  unsigned short* qp = q + (size_t)row * 64;
  const float q1 = bf2f(qp[f]), q2 = bf2f(qp[f + 32]);
  qp[f]      = f2bf((q1 * c - q2 * s) * 0.125f);
  qp[f + 32] = f2bf((q1 * s + q2 * c) * 0.125f);
  unsigned short* kp = k + (size_t)row * 64;
  const float k1 = bf2f(kp[f]), k2 = bf2f(kp[f + 32]);
  kp[f]      = f2bf(k1 * c - k2 * s);
  kp[f + 32] = f2bf(k1 * s + k2 * c);
}

// ---------------------------------------------------------------------------
// V [bh][l][64] bf16  ->  Vt [bh][64][l=2048] bf16 (64x64 LDS tiles)
// ---------------------------------------------------------------------------
__global__ __launch_bounds__(256) void transpose_v(const unsigned short* __restrict__ V,
                                                   unsigned short* __restrict__ Vt) {
  __shared__ unsigned short T[64][72];
  const int bh = blockIdx.y, l0 = blockIdx.x * 64;
  const int t = threadIdx.x;
  const int r = t >> 2, c16 = (t & 3) * 16;
  const unsigned short* src = V + (size_t)bh * 2048 * 64 + (size_t)(l0 + r) * 64 + c16;
  *reinterpret_cast<short8*>(&T[r][c16])     = *reinterpret_cast<const short8*>(src);
  *reinterpret_cast<short8*>(&T[r][c16 + 8]) = *reinterpret_cast<const short8*>(src + 8);
  __syncthreads();
  short8 o0, o1;
#pragma unroll
  for (int jj = 0; jj < 8; ++jj) o0[jj] = (short)T[c16 + jj][r];
#pragma unroll
  for (int jj = 0; jj < 8; ++jj) o1[jj] = (short)T[c16 + 8 + jj][r];
  unsigned short* dst = Vt + ((size_t)bh * 64 + r) * 2048 + l0 + c16;
  *reinterpret_cast<short8*>(dst) = o0;
  *reinterpret_cast<short8*>(dst + 8) = o1;
}

// ---------------------------------------------------------------------------
// Flash attention, bf16 MFMA.  Block = 4 waves, 64 q-rows; 32 K/V tiles of 64.
// K/V fragments loaded directly from global (L1-resident); S->LDS f32 for the
// wave-parallel online softmax; P bf16 in LDS (stride 72: conflict-free b128).
// Output bf16 [B,L,C].
// ---------------------------------------------------------------------------
__global__ __launch_bounds__(256) void attn_mfma(const unsigned short* __restrict__ Q,
                                                 const unsigned short* __restrict__ K,
                                                 const unsigned short* __restrict__ Vt,
                                                 unsigned short* __restrict__ O) {
  __shared__ float Ss[64][68];
  __shared__ unsigned short Ps[64][72];
  __shared__ float red_m[64], red_l[64], red_a[64];
  const int bh = blockIdx.y, q0 = blockIdx.x * 64;
  const int t = threadIdx.x, l = t & 63, w = t >> 6;
  const int lr = l & 15, lg = l >> 4;
  const unsigned short* Qb = Q + (size_t)bh * 2048 * 64;
  const unsigned short* Kb = K + (size_t)bh * 2048 * 64;
  const unsigned short* Vb = Vt + (size_t)bh * 64 * 2048;

  short8 qf0 = *reinterpret_cast<const short8*>(Qb + (size_t)(q0 + w * 16 + lr) * 64 + lg * 8);
  short8 qf1 = *reinterpret_cast<const short8*>(Qb + (size_t)(q0 + w * 16 + lr) * 64 + 32 + lg * 8);

  if (t < 64) { red_m[t] = -3.0e38f; red_l[t] = 0.0f; }

  f32x4 oacc[4] = {};
  for (int k0 = 0; k0 < 2048; k0 += 64) {
    // ---- S = Q K^T (scale pre-folded into Q) ----
    f32x4 sacc[4] = {};
#pragma unroll
    for (int n = 0; n < 4; ++n) {
      const unsigned short* kp = Kb + (size_t)(k0 + n * 16 + lr) * 64 + lg * 8;
      short8 kf0 = *reinterpret_cast<const short8*>(kp);
      short8 kf1 = *reinterpret_cast<const short8*>(kp + 32);
      sacc[n] = __builtin_amdgcn_mfma_f32_16x16x32_bf16(qf0, kf0, sacc[n], 0, 0, 0);
      sacc[n] = __builtin_amdgcn_mfma_f32_16x16x32_bf16(qf1, kf1, sacc[n], 0, 0, 0);
    }
#pragma unroll
    for (int n = 0; n < 4; ++n)
#pragma unroll
      for (int r = 0; r < 4; ++r)
        Ss[w * 16 + lg * 4 + r][n * 16 + lr] = sacc[n][r];
    __syncthreads();

    // ---- online softmax: 4 threads per row ----
    {
      const int sr = t >> 2, c0 = (t & 3) * 16;
      float sv[16];
      float mx = -3.0e38f;
#pragma unroll
      for (int c = 0; c < 16; ++c) { sv[c] = Ss[sr][c0 + c]; mx = fmaxf(mx, sv[c]); }
      mx = fmaxf(mx, __shfl_xor(mx, 1));
      mx = fmaxf(mx, __shfl_xor(mx, 2));
      const float m_old = red_m[sr];
      const float m_new = fmaxf(m_old, mx);
      float sum = 0.0f;
#pragma unroll
      for (int c = 0; c < 16; ++c) {
        float p = __expf(sv[c] - m_new);
        sum += p;
        Ps[sr][c0 + c] = f2bf(p);
      }
      sum += __shfl_xor(sum, 1);
      sum += __shfl_xor(sum, 2);
      if ((t & 3) == 0) {
        const float al = __expf(m_old - m_new);
        red_a[sr] = al;
        red_m[sr] = m_new;
        red_l[sr] = red_l[sr] * al + sum;
      }
    }
    __syncthreads();

    // ---- rescale O, then O += P V ----
    float al[4];
#pragma unroll
    for (int r = 0; r < 4; ++r) al[r] = red_a[w * 16 + lg * 4 + r];
#pragma unroll
    for (int n = 0; n < 4; ++n)
#pragma unroll
      for (int r = 0; r < 4; ++r) oacc[n][r] *= al[r];

    short8 pa0 = *reinterpret_cast<const short8*>(&Ps[w * 16 + lr][lg * 8]);
    short8 pa1 = *reinterpret_cast<const short8*>(&Ps[w * 16 + lr][32 + lg * 8]);
#pragma unroll
    for (int n = 0; n < 4; ++n) {
      const unsigned short* vp = Vb + (size_t)(n * 16 + lr) * 2048 + k0 + lg * 8;
      short8 vf0 = *reinterpret_cast<const short8*>(vp);
      short8 vf1 = *reinterpret_cast<const short8*>(vp + 32);
      oacc[n] = __builtin_amdgcn_mfma_f32_16x16x32_bf16(pa0, vf0, oacc[n], 0, 0, 0);
      oacc[n] = __builtin_amdgcn_mfma_f32_16x16x32_bf16(pa1, vf1, oacc[n], 0, 0, 0);
    }
  }

  // ---- normalize + store bf16 [B,L,C] ----
  const int b = bh >> 4, h = bh & 15;
  float inv[4];
#pragma unroll
  for (int r = 0; r < 4; ++r) inv[r] = 1.0f / red_l[w * 16 + lg * 4 + r];
  unsigned short* Ob = O + ((size_t)(b * 2048 + q0 + w * 16)) * 1024 + h * 64;
#pragma unroll
  for (int n = 0; n < 4; ++n)
#pragma unroll
    for (int r = 0; r < 4; ++r)
      Ob[(size_t)(lg * 4 + r) * 1024 + n * 16 + lr] = f2bf(oacc[n][r] * inv[r]);
}

// ---------------------------------------------------------------------------
extern "C" void kernel_launch(void* const* d_in, const int* in_sizes, int n_in,
                              void* d_out, int out_size, void* d_ws, size_t ws_size,
                              hipStream_t stream) {
  const float* x          = (const float*)d_in[0];
  const float* w_qkv      = (const float*)d_in[1];
  const float* b_qkv      = (const float*)d_in[2];
  const float* w_out      = (const float*)d_in[3];
  const float* b_out      = (const float*)d_in[4];
  const float* rope_freqs = (const float*)d_in[5];
  float* out = (float*)d_out;

  char* ws = (char*)d_ws;
  // byte offsets (all 16B-aligned)
  unsigned short* x_bf    = (unsigned short*)(ws + 0);          // 8,388,608 B (also attn_bf later)
  unsigned short* attn_bf = x_bf;                               // alias: x_bf dead after qkv GEMM
  unsigned short* q_bf    = (unsigned short*)(ws + 8388608);
  unsigned short* k_bf    = (unsigned short*)(ws + 16777216);
  unsigned short* v_bf    = (unsigned short*)(ws + 25165824);
  unsigned short* v_t     = (unsigned short*)(ws + 33554432);
  unsigned short* wqkvT   = (unsigned short*)(ws + 41943040);   // 6,291,456 B
  unsigned short* woutT   = (unsigned short*)(ws + 48234496);   // 2,097,152 B  (total 50.3 MB)

  // 1) convert x -> bf16
  hipLaunchKernelGGL(cvt_f32_bf16, dim3(1024), dim3(256), 0, stream, x, x_bf, 1048576);
  // 2) transpose-convert weights to [N][K] bf16
  hipLaunchKernelGGL(transpose_cvt, dim3(48, 16), dim3(256), 0, stream, w_qkv, wqkvT, 1024, 3072);
  hipLaunchKernelGGL(transpose_cvt, dim3(16, 16), dim3(256), 0, stream, w_out, woutT, 1024, 1024);
  // 3) QKV projection -> bf16 q,k,v in [B,H,L,HD]
  hipLaunchKernelGGL((mm128<0>), dim3(24, 32), dim3(256), 0, stream,
                     x_bf, wqkvT, b_qkv, q_bf, k_bf, v_bf, (float*)nullptr);
  // 4) RoPE in-place (q scaled by 0.125)
  hipLaunchKernelGGL(rope_bf, dim3(8192), dim3(256), 0, stream, q_bf, k_bf, rope_freqs);
  // 5) V -> Vt [bh][d][l]
  hipLaunchKernelGGL(transpose_v, dim3(32, 32), dim3(256), 0, stream, v_bf, v_t);
  // 6) attention -> bf16 [B,L,C]
  hipLaunchKernelGGL(attn_mfma, dim3(32, 32), dim3(256), 0, stream, q_bf, k_bf, v_t, attn_bf);
  // 7) output projection -> f32 d_out
  hipLaunchKernelGGL((mm128<1>), dim3(8, 32), dim3(256), 0, stream,
                     attn_bf, woutT, b_out,
                     (unsigned short*)nullptr, (unsigned short*)nullptr, (unsigned short*)nullptr, out);
}

// Round 3
// 301.328 us; speedup vs baseline: 3.6079x; 1.3830x over previous
//
#include <hip/hip_runtime.h>
#include <cstddef>
#include <cstdint>

// B=2, L=2048, H=16, HD=64, C=1024. All matmuls on bf16 MFMA, f32 accum.

typedef __attribute__((ext_vector_type(8))) short short8;
typedef __attribute__((ext_vector_type(4))) float f32x4;
typedef __attribute__((ext_vector_type(4))) unsigned short ushort4_t;

__device__ __forceinline__ unsigned short f2bf(float f) {
  union { float f; unsigned int u; } c{f};
  unsigned int u = c.u;
  u += 0x7fff + ((u >> 16) & 1);   // round-to-nearest-even
  return (unsigned short)(u >> 16);
}
__device__ __forceinline__ float bf2f(unsigned short h) {
  union { unsigned int u; float f; } c{((unsigned int)h) << 16};
  return c.f;
}

// ---------------------------------------------------------------------------
// f32 -> bf16 elementwise convert (vectorized)
// ---------------------------------------------------------------------------
__global__ __launch_bounds__(256) void cvt_f32_bf16(const float* __restrict__ src,
                                                    unsigned short* __restrict__ dst,
                                                    int n4) {
  int i = blockIdx.x * 256 + threadIdx.x;
  int stride = gridDim.x * 256;
  for (; i < n4; i += stride) {
    float4 v = reinterpret_cast<const float4*>(src)[i];
    ushort4_t o;
    o.x = f2bf(v.x); o.y = f2bf(v.y); o.z = f2bf(v.z); o.w = f2bf(v.w);
    reinterpret_cast<ushort4_t*>(dst)[i] = o;
  }
}

// ---------------------------------------------------------------------------
// W[K][N] f32  ->  WT[N][K] bf16   (64x64 tiles via LDS)
// ---------------------------------------------------------------------------
__global__ __launch_bounds__(256) void transpose_cvt(const float* __restrict__ W,
                                                     unsigned short* __restrict__ WT,
                                                     int K, int N) {
  __shared__ float T[64][65];
  const int n0 = blockIdx.x * 64, k0 = blockIdx.y * 64;
  const int t = threadIdx.x;
  const int r = t >> 4, c4 = (t & 15) * 4;
#pragma unroll
  for (int rr = 0; rr < 4; ++rr) {
    int kk = rr * 16 + r;
    float4 v = *reinterpret_cast<const float4*>(W + (size_t)(k0 + kk) * N + n0 + c4);
    T[kk][c4 + 0] = v.x; T[kk][c4 + 1] = v.y; T[kk][c4 + 2] = v.z; T[kk][c4 + 3] = v.w;
  }
  __syncthreads();
#pragma unroll
  for (int rr = 0; rr < 4; ++rr) {
    int nn = rr * 16 + r;
    ushort4_t o;
    o.x = f2bf(T[c4 + 0][nn]); o.y = f2bf(T[c4 + 1][nn]);
    o.z = f2bf(T[c4 + 2][nn]); o.w = f2bf(T[c4 + 3][nn]);
    *reinterpret_cast<ushort4_t*>(WT + (size_t)(n0 + nn) * K + k0 + c4) = o;
  }
}

// ---------------------------------------------------------------------------
// 128x128x(BK=32) bf16 MFMA GEMM, K=1024 fixed.  A[M][1024] bf16,
// Bt[N][1024] bf16 (pre-transposed).  EPI 0: qkv scatter epilogue (bf16
// q/k/v in [B,H,L,HD]);  EPI 1: f32 out + bias.
// ---------------------------------------------------------------------------
template <int EPI>
__global__ __launch_bounds__(256) void mm128(const unsigned short* __restrict__ A,
                                             const unsigned short* __restrict__ Bt,
                                             const float* __restrict__ bias,
                                             unsigned short* __restrict__ q,
                                             unsigned short* __restrict__ k,
                                             unsigned short* __restrict__ v,
                                             float* __restrict__ outf) {
  __shared__ unsigned short As[128][40];
  __shared__ unsigned short Bs[128][40];
  const int m0 = blockIdx.y * 128, n0 = blockIdx.x * 128;
  const int t = threadIdx.x, l = t & 63, w = t >> 6;
  const int wm = w >> 1, wn = w & 1;
  const int lr = l & 15, lg = l >> 4;
  const int lrow = t >> 1, lk = (t & 1) * 16;

  f32x4 acc[4][4] = {};
  for (int k0 = 0; k0 < 1024; k0 += 32) {
    const unsigned short* ap = A + (size_t)(m0 + lrow) * 1024 + k0 + lk;
    const unsigned short* bp = Bt + (size_t)(n0 + lrow) * 1024 + k0 + lk;
    short8 av0 = *reinterpret_cast<const short8*>(ap);
    short8 av1 = *reinterpret_cast<const short8*>(ap + 8);
    short8 bv0 = *reinterpret_cast<const short8*>(bp);
    short8 bv1 = *reinterpret_cast<const short8*>(bp + 8);
    __syncthreads();
    *reinterpret_cast<short8*>(&As[lrow][lk]) = av0;
    *reinterpret_cast<short8*>(&As[lrow][lk + 8]) = av1;
    *reinterpret_cast<short8*>(&Bs[lrow][lk]) = bv0;
    *reinterpret_cast<short8*>(&Bs[lrow][lk + 8]) = bv1;
    __syncthreads();
    short8 af[4], bf[4];
#pragma unroll
    for (int i = 0; i < 4; ++i)
      af[i] = *reinterpret_cast<const short8*>(&As[wm * 64 + i * 16 + lr][lg * 8]);
#pragma unroll
    for (int j = 0; j < 4; ++j)
      bf[j] = *reinterpret_cast<const short8*>(&Bs[wn * 64 + j * 16 + lr][lg * 8]);
#pragma unroll
    for (int i = 0; i < 4; ++i)
#pragma unroll
      for (int j = 0; j < 4; ++j)
        acc[i][j] = __builtin_amdgcn_mfma_f32_16x16x32_bf16(af[i], bf[j], acc[i][j], 0, 0, 0);
  }

  if constexpr (EPI == 0) {
#pragma unroll
    for (int j = 0; j < 4; ++j) {
      const int n = n0 + wn * 64 + j * 16 + lr;
      const float bb = bias[n];
      const int s = n >> 10, cc = n & 1023, h = cc >> 6, d = cc & 63;
      unsigned short* dst = (s == 0) ? q : (s == 1) ? k : v;
#pragma unroll
      for (int i = 0; i < 4; ++i)
#pragma unroll
        for (int r = 0; r < 4; ++r) {
          const int m = m0 + wm * 64 + i * 16 + lg * 4 + r;
          const int b = m >> 11, lseq = m & 2047;
          dst[(size_t)(((b << 4) + h) * 2048 + lseq) * 64 + d] = f2bf(acc[i][j][r] + bb);
        }
    }
  } else {
#pragma unroll
    for (int j = 0; j < 4; ++j) {
      const int n = n0 + wn * 64 + j * 16 + lr;
      const float bb = bias[n];
#pragma unroll
      for (int i = 0; i < 4; ++i)
#pragma unroll
        for (int r = 0; r < 4; ++r) {
          const int m = m0 + wm * 64 + i * 16 + lg * 4 + r;
          outf[(size_t)m * 1024 + n] = acc[i][j][r] + bb;
        }
    }
  }
}

// ---------------------------------------------------------------------------
// RoPE in-place on bf16 q,k ([bh][l][64]); folds 0.125 scale into q.
// ---------------------------------------------------------------------------
__global__ __launch_bounds__(256) void rope_bf(unsigned short* __restrict__ q,
                                               unsigned short* __restrict__ k,
                                               const float* __restrict__ freqs) {
  const int tid = blockIdx.x * 256 + threadIdx.x;
  const int f = tid & 31, row = tid >> 5;
  const int lseq = row & 2047, h = (row >> 11) & 15;
  const float th = (float)lseq * freqs[h * 32 + f];
  float s, c;
  sincosf(th, &s, &c);
  unsigned short* qp = q + (size_t)row * 64;
  const float q1 = bf2f(qp[f]), q2 = bf2f(qp[f + 32]);
  qp[f]      = f2bf((q1 * c - q2 * s) * 0.125f);
  qp[f + 32] = f2bf((q1 * s + q2 * c) * 0.125f);
  unsigned short* kp = k + (size_t)row * 64;
  const float k1 = bf2f(kp[f]), k2 = bf2f(kp[f + 32]);
  kp[f]      = f2bf(k1 * c - k2 * s);
  kp[f + 32] = f2bf(k1 * s + k2 * c);
}

// ---------------------------------------------------------------------------
// V [bh][l][64] bf16  ->  Vt [bh][64][l=2048] bf16 (64x64 LDS tiles)
// ---------------------------------------------------------------------------
__global__ __launch_bounds__(256) void transpose_v(const unsigned short* __restrict__ V,
                                                   unsigned short* __restrict__ Vt) {
  __shared__ unsigned short T[64][72];
  const int bh = blockIdx.y, l0 = blockIdx.x * 64;
  const int t = threadIdx.x;
  const int r = t >> 2, c16 = (t & 3) * 16;
  const unsigned short* src = V + (size_t)bh * 2048 * 64 + (size_t)(l0 + r) * 64 + c16;
  *reinterpret_cast<short8*>(&T[r][c16])     = *reinterpret_cast<const short8*>(src);
  *reinterpret_cast<short8*>(&T[r][c16 + 8]) = *reinterpret_cast<const short8*>(src + 8);
  __syncthreads();
  short8 o0, o1;
#pragma unroll
  for (int jj = 0; jj < 8; ++jj) o0[jj] = (short)T[c16 + jj][r];
#pragma unroll
  for (int jj = 0; jj < 8; ++jj) o1[jj] = (short)T[c16 + 8 + jj][r];
  unsigned short* dst = Vt + ((size_t)bh * 64 + r) * 2048 + l0 + c16;
  *reinterpret_cast<short8*>(dst) = o0;
  *reinterpret_cast<short8*>(dst + 8) = o1;
}

// ---------------------------------------------------------------------------
// Flash attention v2: ZERO barriers.  4 waves/block, each wave owns 32 q-rows
// (2 groups of 16).  Swapped QK^T (mfma(K,Q)) makes q lane-local -> in-register
// online softmax (shfl_xor 16/32 across lg groups only).  P -> B-frag via
// wave-private LDS (stride-72 rows: conflict-free).  Swapped PV with A = Vt
// rows.  K register-double-buffered across tiles.
// ---------------------------------------------------------------------------
__global__ __launch_bounds__(256) void attn_mfma2(const unsigned short* __restrict__ Q,
                                                  const unsigned short* __restrict__ K,
                                                  const unsigned short* __restrict__ Vt,
                                                  unsigned short* __restrict__ O) {
  __shared__ unsigned short Pb[4][2][16][72];
  const int bh = blockIdx.y, q0 = blockIdx.x * 128;
  const int t = threadIdx.x, l = t & 63, w = t >> 6;
  const int lr = l & 15, lg = l >> 4;
  const unsigned short* Qb = Q + (size_t)bh * 2048 * 64;
  const unsigned short* Kb = K + (size_t)bh * 2048 * 64;
  const unsigned short* Vb = Vt + (size_t)bh * 64 * 2048;
  const int qrow = q0 + w * 32;

  // Q fragments (B-frag of swapped QK): lane holds Q[q=lr][d = h*32 + lg*8 ..]
  short8 qf[2][2];
#pragma unroll
  for (int g = 0; g < 2; ++g)
#pragma unroll
    for (int h = 0; h < 2; ++h)
      qf[g][h] = *reinterpret_cast<const short8*>(Qb + (size_t)(qrow + g * 16 + lr) * 64 + h * 32 + lg * 8);

  f32x4 oacc[2][4] = {};
  float m_run[2] = {-3.0e38f, -3.0e38f};
  float l_run[2] = {0.0f, 0.0f};

  // preload K tile 0 (A-frag: lane holds K[key = n*16+lr][d = h*32 + lg*8 ..])
  short8 kf[4][2];
#pragma unroll
  for (int n = 0; n < 4; ++n)
#pragma unroll
    for (int h = 0; h < 2; ++h)
      kf[n][h] = *reinterpret_cast<const short8*>(Kb + (size_t)(n * 16 + lr) * 64 + h * 32 + lg * 8);

  for (int it = 0; it < 32; ++it) {
    const int k0 = it * 64;
    // V fragments for current tile (A-frag of swapped PV: Vt[d][key])
    short8 vf[4][2];
#pragma unroll
    for (int sub = 0; sub < 4; ++sub)
#pragma unroll
      for (int kb = 0; kb < 2; ++kb)
        vf[sub][kb] = *reinterpret_cast<const short8*>(Vb + (size_t)(sub * 16 + lr) * 2048 + k0 + kb * 32 + lg * 8);
    // prefetch next K tile
    short8 kn[4][2];
    const int k1 = (it < 31) ? k0 + 64 : k0;
#pragma unroll
    for (int n = 0; n < 4; ++n)
#pragma unroll
      for (int h = 0; h < 2; ++h)
        kn[n][h] = *reinterpret_cast<const short8*>(Kb + (size_t)(k1 + n * 16 + lr) * 64 + h * 32 + lg * 8);

    // ---- S^T = K Q^T : lane holds S[key = n*16 + lg*4 + r][q = lr] ----
    f32x4 sacc[2][4] = {};
#pragma unroll
    for (int g = 0; g < 2; ++g)
#pragma unroll
      for (int n = 0; n < 4; ++n) {
        sacc[g][n] = __builtin_amdgcn_mfma_f32_16x16x32_bf16(kf[n][0], qf[g][0], sacc[g][n], 0, 0, 0);
        sacc[g][n] = __builtin_amdgcn_mfma_f32_16x16x32_bf16(kf[n][1], qf[g][1], sacc[g][n], 0, 0, 0);
      }

    // ---- in-register online softmax (per q-col = lr), then P -> LDS ----
#pragma unroll
    for (int g = 0; g < 2; ++g) {
      float mx = sacc[g][0][0];
#pragma unroll
      for (int n = 0; n < 4; ++n)
#pragma unroll
        for (int r = 0; r < 4; ++r) mx = fmaxf(mx, sacc[g][n][r]);
      mx = fmaxf(mx, __shfl_xor(mx, 16));
      mx = fmaxf(mx, __shfl_xor(mx, 32));
      const float m_new = fmaxf(m_run[g], mx);
      float ssum = 0.0f;
      ushort4_t pk[4];
#pragma unroll
      for (int n = 0; n < 4; ++n)
#pragma unroll
        for (int r = 0; r < 4; ++r) {
          const float p = __expf(sacc[g][n][r] - m_new);
          ssum += p;
          pk[n][r] = f2bf(p);
        }
      ssum += __shfl_xor(ssum, 16);
      ssum += __shfl_xor(ssum, 32);
      const float alpha = __expf(m_run[g] - m_new);
      m_run[g] = m_new;
      l_run[g] = l_run[g] * alpha + ssum;
#pragma unroll
      for (int sub = 0; sub < 4; ++sub)
#pragma unroll
        for (int r = 0; r < 4; ++r) oacc[g][sub][r] *= alpha;
#pragma unroll
      for (int n = 0; n < 4; ++n)
        *reinterpret_cast<ushort4_t*>(&Pb[w][g][lr][n * 16 + lg * 4]) = pk[n];
    }

    // ---- read P as B-frags: lane holds P[q=lr][key = kb*32 + lg*8 ..] ----
    short8 pb[2][2];
#pragma unroll
    for (int g = 0; g < 2; ++g)
#pragma unroll
      for (int kb = 0; kb < 2; ++kb)
        pb[g][kb] = *reinterpret_cast<const short8*>(&Pb[w][g][lr][kb * 32 + lg * 8]);

    // ---- O^T += V^T P^T : lane holds O[d = sub*16 + lg*4 + r][q = lr] ----
#pragma unroll
    for (int g = 0; g < 2; ++g)
#pragma unroll
      for (int sub = 0; sub < 4; ++sub) {
        oacc[g][sub] = __builtin_amdgcn_mfma_f32_16x16x32_bf16(vf[sub][0], pb[g][0], oacc[g][sub], 0, 0, 0);
        oacc[g][sub] = __builtin_amdgcn_mfma_f32_16x16x32_bf16(vf[sub][1], pb[g][1], oacc[g][sub], 0, 0, 0);
      }

    // roll K double-buffer
#pragma unroll
    for (int n = 0; n < 4; ++n)
#pragma unroll
      for (int h = 0; h < 2; ++h) kf[n][h] = kn[n][h];
  }

  // ---- normalize + store bf16 [B,L,C] ----
  const int b = bh >> 4, h = bh & 15;
#pragma unroll
  for (int g = 0; g < 2; ++g) {
    const float inv = 1.0f / l_run[g];
    unsigned short* Ob = O + ((size_t)(b * 2048 + qrow + g * 16 + lr)) * 1024 + h * 64;
#pragma unroll
    for (int sub = 0; sub < 4; ++sub) {
      ushort4_t o;
#pragma unroll
      for (int r = 0; r < 4; ++r) o[r] = f2bf(oacc[g][sub][r] * inv);
      *reinterpret_cast<ushort4_t*>(Ob + sub * 16 + lg * 4) = o;
    }
  }
}

// ---------------------------------------------------------------------------
extern "C" void kernel_launch(void* const* d_in, const int* in_sizes, int n_in,
                              void* d_out, int out_size, void* d_ws, size_t ws_size,
                              hipStream_t stream) {
  const float* x          = (const float*)d_in[0];
  const float* w_qkv      = (const float*)d_in[1];
  const float* b_qkv      = (const float*)d_in[2];
  const float* w_out      = (const float*)d_in[3];
  const float* b_out      = (const float*)d_in[4];
  const float* rope_freqs = (const float*)d_in[5];
  float* out = (float*)d_out;

  char* ws = (char*)d_ws;
  unsigned short* x_bf    = (unsigned short*)(ws + 0);          // 8 MB (aliased by attn_bf)
  unsigned short* attn_bf = x_bf;
  unsigned short* q_bf    = (unsigned short*)(ws + 8388608);
  unsigned short* k_bf    = (unsigned short*)(ws + 16777216);
  unsigned short* v_bf    = (unsigned short*)(ws + 25165824);
  unsigned short* v_t     = (unsigned short*)(ws + 33554432);
  unsigned short* wqkvT   = (unsigned short*)(ws + 41943040);
  unsigned short* woutT   = (unsigned short*)(ws + 48234496);

  hipLaunchKernelGGL(cvt_f32_bf16, dim3(1024), dim3(256), 0, stream, x, x_bf, 1048576);
  hipLaunchKernelGGL(transpose_cvt, dim3(48, 16), dim3(256), 0, stream, w_qkv, wqkvT, 1024, 3072);
  hipLaunchKernelGGL(transpose_cvt, dim3(16, 16), dim3(256), 0, stream, w_out, woutT, 1024, 1024);
  hipLaunchKernelGGL((mm128<0>), dim3(24, 32), dim3(256), 0, stream,
                     x_bf, wqkvT, b_qkv, q_bf, k_bf, v_bf, (float*)nullptr);
  hipLaunchKernelGGL(rope_bf, dim3(8192), dim3(256), 0, stream, q_bf, k_bf, rope_freqs);
  hipLaunchKernelGGL(transpose_v, dim3(32, 32), dim3(256), 0, stream, v_bf, v_t);
  hipLaunchKernelGGL(attn_mfma2, dim3(16, 32), dim3(256), 0, stream, q_bf, k_bf, v_t, attn_bf);
  hipLaunchKernelGGL((mm128<1>), dim3(8, 32), dim3(256), 0, stream,
                     attn_bf, woutT, b_out,
                     (unsigned short*)nullptr, (unsigned short*)nullptr, (unsigned short*)nullptr, out);
}